// Round 1
// baseline (129.418 us; speedup 1.0000x reference)
//
#include <hip/hip_runtime.h>

#define BB 256
#define SS 512
#define DD 64
#define LN_EPS 1e-5f

// ws layout per type (floats), stride 256:
// [0]=alpha  [1]=gamma  [2..7]=G11,G22,G33,G12,G13,G23
// [8..71]=pw_centered  [72..135]=u_centered  [136..199]=e_centered
#define WS_TYPE_STRIDE 256

__global__ __launch_bounds__(64) void prep_kernel(
    const float* __restrict__ proj_w, const float* __restrict__ proj_b,
    const float* __restrict__ sa_in_w, const float* __restrict__ sa_in_b,
    const float* __restrict__ sa_out_w, const float* __restrict__ sa_out_b,
    const float* __restrict__ ca_in_w, const float* __restrict__ ca_in_b,
    const float* __restrict__ ca_out_w, const float* __restrict__ ca_out_b,
    float* __restrict__ ws)
{
    const int d = threadIdx.x; // 0..63
    __shared__ float aq[DD], ak[DD], av[DD], cq[DD], ck[DD], cv[DD];
    __shared__ float uu[DD], ee[DD];

    for (int type = 0; type < 2; ++type) {
        const float* in_w  = type ? ca_in_w  : sa_in_w;
        const float* in_b  = type ? ca_in_b  : sa_in_b;
        const float* out_w = type ? ca_out_w : sa_out_w;
        const float* out_b = type ? ca_out_b : sa_out_b;
        float* w = ws + type * WS_TYPE_STRIDE;

        float s_aq=0.f, s_ak=0.f, s_av=0.f, s_cq=0.f, s_ck=0.f, s_cv=0.f;
        for (int e = 0; e < DD; ++e) {
            float pwv = proj_w[e], pbv = proj_b[e];
            float wq = in_w[d*DD + e];
            float wk = in_w[(DD + d)*DD + e];
            float wv = in_w[(2*DD + d)*DD + e];
            s_aq += wq*pwv; s_ak += wk*pwv; s_av += wv*pwv;
            s_cq += wq*pbv; s_ck += wk*pbv; s_cv += wv*pbv;
        }
        s_cq += in_b[d]; s_ck += in_b[DD + d]; s_cv += in_b[2*DD + d];
        aq[d]=s_aq; ak[d]=s_ak; av[d]=s_av; cq[d]=s_cq; ck[d]=s_ck; cv[d]=s_cv;
        __syncthreads();

        // u = Wo @ av ; w0 = Wo @ cv + bo ; e = pb + w0
        float su=0.f, sw0=0.f;
        for (int e = 0; e < DD; ++e) {
            float wo = out_w[d*DD + e];
            su  += wo*av[e];
            sw0 += wo*cv[e];
        }
        sw0 += out_b[d];
        uu[d] = su;
        ee[d] = proj_b[d] + sw0;
        __syncthreads();

        // redundant per-thread scalar computations (trivial cost)
        float alpha=0.f, gamma=0.f, m_pw=0.f, m_u=0.f, m_e=0.f;
        for (int e = 0; e < DD; ++e) {
            alpha += aq[e]*ak[e];
            gamma += cq[e]*ak[e];
            m_pw  += proj_w[e];
            m_u   += uu[e];
            m_e   += ee[e];
        }
        alpha *= 0.125f;           // /sqrt(D) = /8
        gamma *= 0.125f;
        m_pw *= (1.0f/DD); m_u *= (1.0f/DD); m_e *= (1.0f/DD);

        float G11=0.f,G22=0.f,G33=0.f,G12=0.f,G13=0.f,G23=0.f;
        for (int e = 0; e < DD; ++e) {
            float a  = proj_w[e]-m_pw;
            float bb = uu[e]-m_u;
            float c  = ee[e]-m_e;
            G11 += a*a;  G22 += bb*bb; G33 += c*c;
            G12 += a*bb; G13 += a*c;   G23 += bb*c;
        }
        G11*= (1.0f/DD); G22*=(1.0f/DD); G33*=(1.0f/DD);
        G12*= (1.0f/DD); G13*=(1.0f/DD); G23*=(1.0f/DD);

        w[8   + d] = proj_w[d] - m_pw;
        w[72  + d] = uu[d] - m_u;
        w[136 + d] = ee[d] - m_e;
        if (d == 0) {
            w[0]=alpha; w[1]=gamma;
            w[2]=G11; w[3]=G22; w[4]=G33; w[5]=G12; w[6]=G13; w[7]=G23;
        }
        __syncthreads();
    }
}

__global__ __launch_bounds__(256) void attn_kernel(
    const float* __restrict__ x_src, const float* __restrict__ x_tgt,
    const float* __restrict__ sa_ln_g, const float* __restrict__ sa_ln_b,
    const float* __restrict__ ca_ln_g, const float* __restrict__ ca_ln_b,
    const float* __restrict__ ws, float* __restrict__ out)
{
    const int tid  = threadIdx.x;
    const int b    = blockIdx.x / 3;
    const int task = blockIdx.x % 3;
    // task 0: sa_src (x=xs, y=xs, sa params) -> z_src_private @ offset B*D
    // task 1: sa_tgt (x=xt, y=xt, sa params) -> z_tgt_private @ offset 2*B*D
    // task 2: ca     (x=xs, y=xt, ca params) -> z_shared      @ offset 0
    const float* xq_g = (task == 1) ? (x_tgt + b*SS) : (x_src + b*SS);
    const float* y_g  = (task == 0) ? (x_src + b*SS) : (x_tgt + b*SS);
    const int type    = (task == 2) ? 1 : 0;
    const float* w  = ws + type * WS_TYPE_STRIDE;
    const float* g  = type ? ca_ln_g : sa_ln_g;
    const float* lb = type ? ca_ln_b : sa_ln_b;
    const int out_base = ((task==0) ? BB*DD : (task==1) ? 2*BB*DD : 0) + b*DD;

    __shared__ float xs_l[SS];
    __shared__ float ys_l[SS];
    __shared__ float rmax[4], rmin[4], rP[4], rT[4], rI[4];
    __shared__ float bc[5]; // ymax, ymin, P, T, I

    const int wave = tid >> 6, lane = tid & 63;

    // stage x and y into LDS
    float xa = xq_g[tid], xb = xq_g[tid + 256];
    float y0 = y_g[tid],  y1 = y_g[tid + 256];
    xs_l[tid] = xa; xs_l[tid + 256] = xb;
    ys_l[tid] = y0; ys_l[tid + 256] = y1;

    // block reduce ymax / ymin (for stable exp)
    float mymax = fmaxf(y0, y1), mymin = fminf(y0, y1);
    #pragma unroll
    for (int o = 32; o > 0; o >>= 1) {
        mymax = fmaxf(mymax, __shfl_down(mymax, o));
        mymin = fminf(mymin, __shfl_down(mymin, o));
    }
    if (lane == 0) { rmax[wave] = mymax; rmin[wave] = mymin; }
    __syncthreads();
    if (tid == 0) {
        bc[0] = fmaxf(fmaxf(rmax[0], rmax[1]), fmaxf(rmax[2], rmax[3]));
        bc[1] = fminf(fminf(rmin[0], rmin[1]), fminf(rmin[2], rmin[3]));
    }
    __syncthreads();
    const float ymax = bc[0], ymin = bc[1];

    const float alpha = w[0], gamma = w[1];
    const float G11=w[2], G22=w[3], G33=w[4], G12=w[5], G13=w[6], G23=w[7];

    // two query rows per thread
    const float xq0 = xa, xq1 = xb;
    const float c0 = alpha*xq0 + gamma;
    const float c1 = alpha*xq1 + gamma;
    const float m0 = fmaxf(c0*ymax, c0*ymin);
    const float m1 = fmaxf(c1*ymax, c1*ymin);

    float den0=0.f, num0=0.f, den1=0.f, num1=0.f;
    #pragma unroll 2
    for (int k = 0; k < SS; k += 4) {
        float4 yv = *(const float4*)&ys_l[k];   // LDS broadcast
        float E;
        E = __expf(c0*yv.x - m0); den0 += E; num0 += yv.x*E;
        E = __expf(c1*yv.x - m1); den1 += E; num1 += yv.x*E;
        E = __expf(c0*yv.y - m0); den0 += E; num0 += yv.y*E;
        E = __expf(c1*yv.y - m1); den1 += E; num1 += yv.y*E;
        E = __expf(c0*yv.z - m0); den0 += E; num0 += yv.z*E;
        E = __expf(c1*yv.z - m1); den1 += E; num1 += yv.z*E;
        E = __expf(c0*yv.w - m0); den0 += E; num0 += yv.w*E;
        E = __expf(c1*yv.w - m1); den1 += E; num1 += yv.w*E;
    }
    const float t0 = num0/den0, t1 = num1/den1;

    float var0 = xq0*xq0*G11 + t0*t0*G22 + G33 + 2.f*(xq0*t0*G12 + xq0*G13 + t0*G23);
    float var1 = xq1*xq1*G11 + t1*t1*G22 + G33 + 2.f*(xq1*t1*G12 + xq1*G13 + t1*G23);
    const float inv0 = rsqrtf(var0 + LN_EPS);
    const float inv1 = rsqrtf(var1 + LN_EPS);

    float pP = xq0*inv0 + xq1*inv1;
    float pT = t0*inv0  + t1*inv1;
    float pI = inv0 + inv1;
    #pragma unroll
    for (int o = 32; o > 0; o >>= 1) {
        pP += __shfl_down(pP, o);
        pT += __shfl_down(pT, o);
        pI += __shfl_down(pI, o);
    }
    if (lane == 0) { rP[wave] = pP; rT[wave] = pT; rI[wave] = pI; }
    __syncthreads();
    if (tid == 0) {
        bc[2] = (rP[0]+rP[1]+rP[2]+rP[3]) * (1.0f/SS);
        bc[3] = (rT[0]+rT[1]+rT[2]+rT[3]) * (1.0f/SS);
        bc[4] = (rI[0]+rI[1]+rI[2]+rI[3]) * (1.0f/SS);
    }
    __syncthreads();

    if (tid < DD) {
        const float P = bc[2], T = bc[3], I = bc[4];
        float z = (P*w[8+tid] + T*w[72+tid] + I*w[136+tid]) * g[tid] + lb[tid];
        out[out_base + tid] = z;
    }
}

extern "C" void kernel_launch(void* const* d_in, const int* in_sizes, int n_in,
                              void* d_out, int out_size, void* d_ws, size_t ws_size,
                              hipStream_t stream) {
    const float* x_src    = (const float*)d_in[0];
    const float* x_tgt    = (const float*)d_in[1];
    const float* proj_w   = (const float*)d_in[2];
    const float* proj_b   = (const float*)d_in[3];
    const float* sa_in_w  = (const float*)d_in[4];
    const float* sa_in_b  = (const float*)d_in[5];
    const float* sa_out_w = (const float*)d_in[6];
    const float* sa_out_b = (const float*)d_in[7];
    const float* sa_ln_g  = (const float*)d_in[8];
    const float* sa_ln_b  = (const float*)d_in[9];
    const float* ca_in_w  = (const float*)d_in[10];
    const float* ca_in_b  = (const float*)d_in[11];
    const float* ca_out_w = (const float*)d_in[12];
    const float* ca_out_b = (const float*)d_in[13];
    const float* ca_ln_g  = (const float*)d_in[14];
    const float* ca_ln_b  = (const float*)d_in[15];
    float* ws  = (float*)d_ws;
    float* out = (float*)d_out;

    prep_kernel<<<1, 64, 0, stream>>>(proj_w, proj_b,
                                      sa_in_w, sa_in_b, sa_out_w, sa_out_b,
                                      ca_in_w, ca_in_b, ca_out_w, ca_out_b, ws);
    attn_kernel<<<BB*3, 256, 0, stream>>>(x_src, x_tgt,
                                          sa_ln_g, sa_ln_b, ca_ln_g, ca_ln_b,
                                          ws, out);
}

// Round 2
// 118.179 us; speedup vs baseline: 1.0951x; 1.0951x over previous
//
#include <hip/hip_runtime.h>

#define BB 256
#define SS 512
#define DD 64
#define LN_EPS 1e-5f
#define L2E 1.4426950408889634f

// ws layout per type (floats), stride 256:
// [0]=alpha  [1]=gamma  [2..7]=G11,G22,G33,G12,G13,G23
// [8..71]=pw_centered  [72..135]=u_centered  [136..199]=e_centered
#define WS_TYPE_STRIDE 256

typedef float v2f __attribute__((ext_vector_type(2)));

__device__ __forceinline__ float fexp2(float x) {
#if __has_builtin(__builtin_amdgcn_exp2f)
    return __builtin_amdgcn_exp2f(x);
#else
    float r; asm("v_exp_f32 %0, %1" : "=v"(r) : "v"(x)); return r;
#endif
}

// One block, 1024 threads. Stage 1: 12 matvecs (q/k/v blocks x {pw,pb} x 2 types)
// = 768 independent 64-long dots. Stage 2: u=Wo@av, w0=Wo@cv+bo (4 matvecs=256
// dots). Stage 3: scalars + Gram via wave shuffles (wave w handles type w).
__global__ __launch_bounds__(1024) void prep_kernel(
    const float* __restrict__ proj_w, const float* __restrict__ proj_b,
    const float* __restrict__ sa_in_w, const float* __restrict__ sa_in_b,
    const float* __restrict__ sa_out_w, const float* __restrict__ sa_out_b,
    const float* __restrict__ ca_in_w, const float* __restrict__ ca_in_b,
    const float* __restrict__ ca_out_w, const float* __restrict__ ca_out_b,
    float* __restrict__ ws)
{
    const int tid = threadIdx.x;
    __shared__ float sv[2][6][DD];          // aq,ak,av,cq,ck,cv per type
    __shared__ float suu[2][DD], see[2][DD];

    // ---- stage 1 ----
    if (tid < 768) {
        const int mat = tid >> 6, d = tid & 63;
        const int type = mat / 6, which = mat % 6;
        const int rb = which % 3;            // 0=q,1=k,2=v
        const int vecsel = which / 3;        // 0=pw, 1=pb
        const float* W = (type ? ca_in_w : sa_in_w) + (rb * DD + d) * DD;
        const float* v = vecsel ? proj_b : proj_w;
        float s = 0.f;
        #pragma unroll
        for (int e = 0; e < DD; e += 4) {
            float4 wv = *(const float4*)(W + e);
            float4 vv = *(const float4*)(v + e);
            s += wv.x * vv.x + wv.y * vv.y + wv.z * vv.z + wv.w * vv.w;
        }
        if (vecsel) s += (type ? ca_in_b : sa_in_b)[rb * DD + d];
        sv[type][which][d] = s;
    }
    __syncthreads();

    // ---- stage 2 ----
    if (tid < 256) {
        const int mat = tid >> 6, d = tid & 63;
        const int type = mat >> 1, which = mat & 1;   // 0: u=Wo@av, 1: w0=Wo@cv+bo
        const float* W = (type ? ca_out_w : sa_out_w) + d * DD;
        const float* v = sv[type][which ? 5 : 2];     // cv : av
        float s = 0.f;
        #pragma unroll
        for (int e = 0; e < DD; e += 4) {
            float4 wv = *(const float4*)(W + e);
            s += wv.x * v[e] + wv.y * v[e + 1] + wv.z * v[e + 2] + wv.w * v[e + 3];
        }
        if (which) {
            s += (type ? ca_out_b : sa_out_b)[d];
            see[type][d] = proj_b[d] + s;             // e = pb + Wo@cv + bo
        } else {
            suu[type][d] = s;                         // u = Wo@av
        }
    }
    __syncthreads();

    // ---- stage 3 ----
    const int wave = tid >> 6, lane = tid & 63;
    if (wave < 2) {
        const int type = wave;
        auto wred = [](float x) {
            #pragma unroll
            for (int o = 32; o > 0; o >>= 1) x += __shfl_down(x, o);
            return __shfl(x, 0);
        };
        const float aq = sv[type][0][lane], ak = sv[type][1][lane];
        const float cq = sv[type][3][lane];
        const float pw = proj_w[lane];
        const float u  = suu[type][lane], e = see[type][lane];

        const float alpha = wred(aq * ak) * 0.125f;   // /sqrt(64)
        const float gamma = wred(cq * ak) * 0.125f;
        const float m_pw = wred(pw) * (1.f / DD);
        const float m_u  = wred(u)  * (1.f / DD);
        const float m_e  = wred(e)  * (1.f / DD);
        const float a  = pw - m_pw;
        const float bb = u  - m_u;
        const float c  = e  - m_e;
        const float G11 = wred(a * a)   * (1.f / DD);
        const float G22 = wred(bb * bb) * (1.f / DD);
        const float G33 = wred(c * c)   * (1.f / DD);
        const float G12 = wred(a * bb)  * (1.f / DD);
        const float G13 = wred(a * c)   * (1.f / DD);
        const float G23 = wred(bb * c)  * (1.f / DD);

        float* w = ws + type * WS_TYPE_STRIDE;
        w[8 + lane] = a; w[72 + lane] = bb; w[136 + lane] = c;
        if (lane == 0) {
            w[0] = alpha; w[1] = gamma;
            w[2] = G11; w[3] = G22; w[4] = G33; w[5] = G12; w[6] = G13; w[7] = G23;
        }
    }
}

// 768 blocks x 512 threads; one query row per thread; key-pairs packed as
// float2 so the backend can use v_pk_fma_f32 / v_pk_add_f32.
__global__ __launch_bounds__(512) void attn_kernel(
    const float* __restrict__ x_src, const float* __restrict__ x_tgt,
    const float* __restrict__ sa_ln_g, const float* __restrict__ sa_ln_b,
    const float* __restrict__ ca_ln_g, const float* __restrict__ ca_ln_b,
    const float* __restrict__ ws, float* __restrict__ out)
{
    const int tid  = threadIdx.x;
    const int b    = blockIdx.x / 3;
    const int task = blockIdx.x % 3;
    // task 0: sa_src (x=xs, y=xs) -> z_src_private @ B*D
    // task 1: sa_tgt (x=xt, y=xt) -> z_tgt_private @ 2*B*D
    // task 2: ca     (x=xs, y=xt) -> z_shared      @ 0
    const float* xq_g = (task == 1) ? (x_tgt + b * SS) : (x_src + b * SS);
    const float* y_g  = (task == 0) ? (x_src + b * SS) : (x_tgt + b * SS);
    const int type    = (task == 2) ? 1 : 0;
    const float* w  = ws + type * WS_TYPE_STRIDE;
    const float* g  = type ? ca_ln_g : sa_ln_g;
    const float* lb = type ? ca_ln_b : sa_ln_b;
    const int out_base = ((task == 0) ? BB * DD : (task == 1) ? 2 * BB * DD : 0) + b * DD;

    __shared__ __align__(16) float ys_l[SS];
    __shared__ float rmax[8], rmin[8], rP[8], rT[8], rI[8];
    __shared__ float bc[5];   // ymax, ymin, P, T, I

    const int wave = tid >> 6, lane = tid & 63;

    const float xq = xq_g[tid];
    const float y  = y_g[tid];
    ys_l[tid] = y;

    float mymax = y, mymin = y;
    #pragma unroll
    for (int o = 32; o > 0; o >>= 1) {
        mymax = fmaxf(mymax, __shfl_down(mymax, o));
        mymin = fminf(mymin, __shfl_down(mymin, o));
    }
    if (lane == 0) { rmax[wave] = mymax; rmin[wave] = mymin; }
    __syncthreads();
    if (tid == 0) {
        float a = rmax[0], bmn = rmin[0];
        #pragma unroll
        for (int i = 1; i < 8; ++i) { a = fmaxf(a, rmax[i]); bmn = fminf(bmn, rmin[i]); }
        bc[0] = a; bc[1] = bmn;
    }
    __syncthreads();
    const float ymax = bc[0], ymin = bc[1];

    const float alpha = w[0], gamma = w[1];
    const float G11 = w[2], G22 = w[3], G33 = w[4], G12 = w[5], G13 = w[6], G23 = w[7];

    const float c   = alpha * xq + gamma;
    const float clf = c * L2E;
    const float nml = -fmaxf(c * ymax, c * ymin) * L2E;   // arg = cl*y + nml <= 0
    const v2f cl  = { clf, clf };
    const v2f nm  = { nml, nml };

    v2f den = { 0.f, 0.f }, num = { 0.f, 0.f };
    #pragma unroll 4
    for (int k = 0; k < SS; k += 8) {
        float4 ya = *(const float4*)&ys_l[k];
        float4 yb = *(const float4*)&ys_l[k + 4];
        v2f y0 = { ya.x, ya.y }, y1 = { ya.z, ya.w };
        v2f y2 = { yb.x, yb.y }, y3 = { yb.z, yb.w };
        v2f a0 = cl * y0 + nm;
        v2f a1 = cl * y1 + nm;
        v2f a2 = cl * y2 + nm;
        v2f a3 = cl * y3 + nm;
        v2f E0 = { fexp2(a0.x), fexp2(a0.y) };
        v2f E1 = { fexp2(a1.x), fexp2(a1.y) };
        v2f E2 = { fexp2(a2.x), fexp2(a2.y) };
        v2f E3 = { fexp2(a3.x), fexp2(a3.y) };
        den += E0; num += y0 * E0;
        den += E1; num += y1 * E1;
        den += E2; num += y2 * E2;
        den += E3; num += y3 * E3;
    }
    const float t = (num.x + num.y) / (den.x + den.y);

    const float var = xq * xq * G11 + t * t * G22 + G33
                    + 2.f * (xq * t * G12 + xq * G13 + t * G23);
    const float inv = rsqrtf(var + LN_EPS);

    float pP = xq * inv, pT = t * inv, pI = inv;
    #pragma unroll
    for (int o = 32; o > 0; o >>= 1) {
        pP += __shfl_down(pP, o);
        pT += __shfl_down(pT, o);
        pI += __shfl_down(pI, o);
    }
    if (lane == 0) { rP[wave] = pP; rT[wave] = pT; rI[wave] = pI; }
    __syncthreads();
    if (tid == 0) {
        float sP = 0.f, sT = 0.f, sI = 0.f;
        #pragma unroll
        for (int i = 0; i < 8; ++i) { sP += rP[i]; sT += rT[i]; sI += rI[i]; }
        bc[2] = sP * (1.f / SS); bc[3] = sT * (1.f / SS); bc[4] = sI * (1.f / SS);
    }
    __syncthreads();

    if (tid < DD) {
        const float P = bc[2], T = bc[3], I = bc[4];
        float z = (P * w[8 + tid] + T * w[72 + tid] + I * w[136 + tid]) * g[tid] + lb[tid];
        out[out_base + tid] = z;
    }
}

extern "C" void kernel_launch(void* const* d_in, const int* in_sizes, int n_in,
                              void* d_out, int out_size, void* d_ws, size_t ws_size,
                              hipStream_t stream) {
    const float* x_src    = (const float*)d_in[0];
    const float* x_tgt    = (const float*)d_in[1];
    const float* proj_w   = (const float*)d_in[2];
    const float* proj_b   = (const float*)d_in[3];
    const float* sa_in_w  = (const float*)d_in[4];
    const float* sa_in_b  = (const float*)d_in[5];
    const float* sa_out_w = (const float*)d_in[6];
    const float* sa_out_b = (const float*)d_in[7];
    const float* sa_ln_g  = (const float*)d_in[8];
    const float* sa_ln_b  = (const float*)d_in[9];
    const float* ca_in_w  = (const float*)d_in[10];
    const float* ca_in_b  = (const float*)d_in[11];
    const float* ca_out_w = (const float*)d_in[12];
    const float* ca_out_b = (const float*)d_in[13];
    const float* ca_ln_g  = (const float*)d_in[14];
    const float* ca_ln_b  = (const float*)d_in[15];
    float* ws  = (float*)d_ws;
    float* out = (float*)d_out;

    prep_kernel<<<1, 1024, 0, stream>>>(proj_w, proj_b,
                                        sa_in_w, sa_in_b, sa_out_w, sa_out_b,
                                        ca_in_w, ca_in_b, ca_out_w, ca_out_b, ws);
    attn_kernel<<<BB * 3, 512, 0, stream>>>(x_src, x_tgt,
                                            sa_ln_g, sa_ln_b, ca_ln_g, ca_ln_b,
                                            ws, out);
}